// Round 11
// baseline (132.150 us; speedup 1.0000x reference)
//
#include <hip/hip_runtime.h>

#define NS 8192
#define EMBED 128
#define ROWCHUNK 512             // grid.y = 16 chunks of 512 rows
#define NTILE (ROWCHUNK / 16)    // 32 A-tiles of 16 rows per chunk
#define AROW 12                  // correction-hist row stride (11 bins + 1 pad)
#define INV64K (1.0f / 65536.0f)

typedef __bf16 bf16x8 __attribute__((ext_vector_type(8)));
typedef float f32x4 __attribute__((ext_vector_type(4)));
typedef float f32x2 __attribute__((ext_vector_type(2)));

// workspace layout (bytes from ws start)
#define OFF_XB  0u               // bf16 [8192][128] = 2 MiB (row-granule-XOR-swizzled)
#define OFF_GS  2097152u         // q16  [8192][4]   cumulative C bins 3..6
#define OFF_GSP 2228224u         // q16  [8192][4]   cumulative Cp bins 3..6
#define OFF_GA  2359296u         // q16  [8192][12]  all-hist corrections
#define OFF_GAP 2752512u         // q16  [8192][12]  pos-hist corrections
#define OFF_CC  3145728u         // int  [128] class counts
#define OFF_AC  3146240u         // float[2] accum + u32 done
#define ZERO_BYTES 1049120u      // OFF_GS .. end (16B multiple)

__device__ inline unsigned short f2bf(float f) {
  unsigned u = __float_as_uint(f);
  u += 0x7fffu + ((u >> 16) & 1u);   // round-to-nearest-even
  return (unsigned short)(u >> 16);
}
__device__ inline float clamp01(float x) { return __builtin_amdgcn_fmed3f(x, 0.f, 1.f); }
__device__ inline f32x2 pkclamp01(f32x2 v) {
  return __builtin_elementwise_min(__builtin_elementwise_max(v, (f32x2){0.f, 0.f}),
                                   (f32x2){1.f, 1.f});
}

// ---- prep: fp32->bf16 convert into XOR-swizzled layout + zero accumulators ----
__global__ __launch_bounds__(256) void prep_kernel(const float* __restrict__ x,
                                                   unsigned short* __restrict__ xb,
                                                   uint4* __restrict__ zbase) {
  const int gid = blockIdx.x * 256 + threadIdx.x;   // 131072 threads: row*16+granule
  const int row = gid >> 4, g = gid & 15;
  const float4 v0 = reinterpret_cast<const float4*>(x)[row * 32 + g * 2];
  const float4 v1 = reinterpret_cast<const float4*>(x)[row * 32 + g * 2 + 1];
  uint4 o;
  o.x = (unsigned)f2bf(v0.x) | ((unsigned)f2bf(v0.y) << 16);
  o.y = (unsigned)f2bf(v0.z) | ((unsigned)f2bf(v0.w) << 16);
  o.z = (unsigned)f2bf(v1.x) | ((unsigned)f2bf(v1.y) << 16);
  o.w = (unsigned)f2bf(v1.z) | ((unsigned)f2bf(v1.w) << 16);
  reinterpret_cast<uint4*>(xb)[row * 16 + (g ^ (row & 7))] = o;
  if (gid < (int)(ZERO_BYTES / 16u)) zbase[gid] = make_uint4(0u, 0u, 0u, 0u);
}

// ---- main: fixed 16-col B frags/wave, A-frags streamed from L2 via a 2-deep
// register pipeline. NO LDS staging, NO barriers in the K-loop. ----
__global__ __launch_bounds__(256, 6) void fastap_main_kernel(
    const unsigned short* __restrict__ xb,
    const int* __restrict__ labels,
    unsigned* __restrict__ gS, unsigned* __restrict__ gSp,
    unsigned* __restrict__ gA, unsigned* __restrict__ gAp,
    int* __restrict__ ccount) {
  __shared__ int sLab[ROWCHUNK];   // this chunk's row labels (read-only after barrier)

  const int tid  = threadIdx.x;
  const int wave = tid >> 6;
  const int lane = tid & 63;
  const int l16  = lane & 15;
  const int quad = lane >> 4;
  const int colBase  = blockIdx.x * 64;       // 128 col strips
  const int rowChunk = blockIdx.y * ROWCHUNK; // 16 row chunks

  if (tid < ROWCHUNK / 4)
    reinterpret_cast<int4*>(sLab)[tid] =
        reinterpret_cast<const int4*>(labels + rowChunk)[tid];

  // fixed B fragments: this wave's 16 cols, K=128 (jcol&7 == l16&7)
  const int jcol = colBase + wave * 16 + l16;
  bf16x8 bfr[4];
  #pragma unroll
  for (int kb = 0; kb < 4; ++kb) {
    const int pg = (kb * 4 + quad) ^ (l16 & 7);
    bfr[kb] = *reinterpret_cast<const bf16x8*>(&xb[jcol * 128 + pg * 8]);
  }
  const int labj = labels[jcol];

  f32x2 C01 = {0.f, 0.f}, C23 = {0.f, 0.f};
  f32x2 Cp01 = {0.f, 0.f}, Cp23 = {0.f, 0.f};

  // per-lane A stream base: row = rowChunk + t*16 + l16 (row&7 == l16&7, so the
  // swizzled granule index pg is tile-invariant); advance 16 rows (4 KB) per tile.
  const unsigned short* srcA = xb + (rowChunk + l16) * 128;
  int go[4];
  #pragma unroll
  for (int kb = 0; kb < 4; ++kb)
    go[kb] = (((kb * 4 + quad) ^ (l16 & 7)) << 3);

  auto loadA = [&](int t, bf16x8* dst) {
    const unsigned short* p = srcA + t * (16 * 128);
    #pragma unroll
    for (int kb = 0; kb < 4; ++kb)
      dst[kb] = *reinterpret_cast<const bf16x8*>(p + go[kb]);
  };

  // one 16-row x 16-col tile from register A-frags; lcr = t*16
  auto tile16 = [&](const bf16x8* af, int lcr) {
    const int4 lr = *reinterpret_cast<const int4*>(&sLab[lcr + quad * 4]);
    f32x4 acc = {0.f, 0.f, 0.f, 0.f};
    acc = __builtin_amdgcn_mfma_f32_16x16x32_bf16(af[0], bfr[0], acc, 0, 0, 0);
    acc = __builtin_amdgcn_mfma_f32_16x16x32_bf16(af[1], bfr[1], acc, 0, 0, 0);
    acc = __builtin_amdgcn_mfma_f32_16x16x32_bf16(af[2], bfr[2], acc, 0, 0, 0);
    acc = __builtin_amdgcn_mfma_f32_16x16x32_bf16(af[3], bfr[3], acc, 0, 0, 0);

    const int labr[4] = {lr.x, lr.y, lr.z, lr.w};
    // fast path: packed f32; register bins 3..6 are EXACT for all t:
    // H[k] = clamp01(5a + (k-4)).
    #pragma unroll
    for (int r = 0; r < 4; ++r) {              // D: row = quad*4+r, col = l16
      const float a = acc[r];                  // cos(i, jcol)
      const float pm = (labr[r] == labj) ? 1.f : 0.f;  // diag fixed in rare path
      const f32x2 av = {a, a}, p2 = {pm, pm};
      const f32x2 d01 = pkclamp01(__builtin_elementwise_fma(av, (f32x2){5.f, 5.f},
                                                            (f32x2){-1.f, 0.f}));
      const f32x2 d23 = pkclamp01(__builtin_elementwise_fma(av, (f32x2){5.f, 5.f},
                                                            (f32x2){1.f, 2.f}));
      C01 += d01; C23 += d23;
      Cp01 = __builtin_elementwise_fma(p2, d01, Cp01);
      Cp23 = __builtin_elementwise_fma(p2, d23, Cp23);
    }

    // one rare check per 4 pairs (abs modifiers are free on v_max)
    const float mabs = fmaxf(fmaxf(fabsf(acc[0]), fabsf(acc[1])),
                             fmaxf(fabsf(acc[2]), fabsf(acc[3])));
    if (__builtin_expect(mabs > 0.4f, 0)) {
      #pragma unroll
      for (int r = 0; r < 4; ++r) {
        const float a = acc[r];
        if (fabsf(a) <= 0.4f) continue;
        const int i = rowChunk + lcr + quad * 4 + r;
        const float d0 = clamp01(fmaf(a, 5.f, -1.f));
        const float d1 = clamp01(a * 5.f);
        const float d2 = clamp01(fmaf(a, 5.f, 1.f));
        const float d3 = clamp01(fmaf(a, 5.f, 2.f));
        if (i == jcol) {
          // diagonal: cancel fast contributions (pm was 1) + bins>=7 base (+1)
          C01 -= (f32x2){d0, d1};  C23 -= (f32x2){d2, d3};
          Cp01 -= (f32x2){d0, d1}; Cp23 -= (f32x2){d2, d3};
          #pragma unroll
          for (int k = 7; k <= 10; ++k)
            atomicAdd(&gA[jcol * AROW + k], (unsigned)(-65536));
        } else {
          const bool isPos = (labr[r] == labj);
          const float t = fmaf(a, -5.f, 5.f);
          #pragma unroll
          for (int k = 0; k <= 2; ++k) {       // assumed cumulative 0
            const float v = clamp01((float)(k + 1) - t);
            const int q = (int)(v * 65536.f + 0.5f);
            if (q) {
              atomicAdd(&gA[jcol * AROW + k], (unsigned)q);
              if (isPos) atomicAdd(&gAp[jcol * AROW + k], (unsigned)q);
            }
          }
          #pragma unroll
          for (int k = 7; k <= 10; ++k) {      // assumed cumulative 1
            const float v = clamp01((float)(k + 1) - t) - 1.f;
            const int q = (int)(v * 65536.f - 0.5f);
            if (q) {
              atomicAdd(&gA[jcol * AROW + k], (unsigned)q);
              if (isPos) atomicAdd(&gAp[jcol * AROW + k], (unsigned)q);
            }
          }
        }
      }
    }
  };

  __syncthreads();             // sLab visible (only barrier in the kernel)

  // class counts: one col-strip per row-chunk counts its 512 rows
  if (blockIdx.x == 0) {
    for (int idx = tid; idx < ROWCHUNK; idx += 256)
      atomicAdd(&ccount[sLab[idx]], 1);
  }

  // 2-deep register pipeline over 32 A-tiles (unroll x2 -> static buffers)
  bf16x8 af0[4], af1[4];
  loadA(0, af0);
  #pragma unroll 1
  for (int t = 0; t < NTILE; t += 2) {
    loadA(t + 1, af1);           // prefetch next while computing current
    tile16(af0, t * 16);
    loadA((t + 2) & (NTILE - 1), af0);   // tail wraps to tile 0: harmless dup load
    tile16(af1, t * 16 + 16);
  }

  // reduce across the 4 quads sharing each column (lane ^16, ^32)
  #pragma unroll
  for (int m = 16; m < 64; m <<= 1) {
    C01.x  += __shfl_xor(C01.x,  m, 64); C01.y  += __shfl_xor(C01.y,  m, 64);
    C23.x  += __shfl_xor(C23.x,  m, 64); C23.y  += __shfl_xor(C23.y,  m, 64);
    Cp01.x += __shfl_xor(Cp01.x, m, 64); Cp01.y += __shfl_xor(Cp01.y, m, 64);
    Cp23.x += __shfl_xor(Cp23.x, m, 64); Cp23.y += __shfl_xor(Cp23.y, m, 64);
  }

  if (quad == 0) {
    const float Cv[4]  = {C01.x, C01.y, C23.x, C23.y};
    const float Cpv[4] = {Cp01.x, Cp01.y, Cp23.x, Cp23.y};
    #pragma unroll
    for (int k = 0; k < 4; ++k) {
      atomicAdd(&gS[jcol * 4 + k],  (unsigned)(int)lrintf(Cv[k]  * 65536.f));
      atomicAdd(&gSp[jcol * 4 + k], (unsigned)(int)lrintf(Cpv[k] * 65536.f));
    }
  }
}

// ---- epilogue: per-row AP + final loss (last block finalizes) ----
__global__ __launch_bounds__(256) void epilogue_kernel(
    const unsigned* __restrict__ gS, const unsigned* __restrict__ gSp,
    const unsigned* __restrict__ gA, const unsigned* __restrict__ gAp,
    const int* __restrict__ labels, const int* __restrict__ ccount,
    float* __restrict__ accum, unsigned* __restrict__ done,
    float* __restrict__ out) {
  const int i = blockIdx.x * 256 + threadIdx.x;
  const int np = ccount[labels[i]] - 1;   // N_pos = classCount - 1
  float ap = 0.f, val = 0.f, HpPrev = 0.f;
  #pragma unroll
  for (int b = 0; b <= 10; ++b) {
    const float baseH  = (b < 3) ? 0.f
                       : (b < 7) ? (float)(int)gS[i * 4 + (b - 3)]  * INV64K : 8192.f;
    const float basePp = (b < 3) ? 0.f
                       : (b < 7) ? (float)(int)gSp[i * 4 + (b - 3)] * INV64K : (float)np;
    const float H  = baseH  + (float)(int)gA[i * AROW + b]  * INV64K;
    const float Hp = basePp + (float)(int)gAp[i * AROW + b] * INV64K;
    const float hp = Hp - HpPrev;
    HpPrev = Hp;
    if (H > 1e-6f) ap += hp * Hp / H;
  }
  if (np > 0) { ap /= (float)np; val = 1.f; } else ap = 0.f;

  __shared__ float sa[256], sv[256];
  sa[threadIdx.x] = ap; sv[threadIdx.x] = val;
  __syncthreads();
  for (int s = 128; s > 0; s >>= 1) {
    if (threadIdx.x < s) {
      sa[threadIdx.x] += sa[threadIdx.x + s];
      sv[threadIdx.x] += sv[threadIdx.x + s];
    }
    __syncthreads();
  }
  if (threadIdx.x == 0) {
    atomicAdd(&accum[0], sa[0]);
    atomicAdd(&accum[1], sv[0]);
    __threadfence();
    const unsigned prev = atomicAdd(done, 1u);
    if (prev == gridDim.x - 1) {
      const float a = atomicAdd(&accum[0], 0.f);   // coherent reads
      const float c = atomicAdd(&accum[1], 0.f);
      out[0] = 1.f - (c > 0.f ? a / c : 0.f);
    }
  }
}

extern "C" void kernel_launch(void* const* d_in, const int* in_sizes, int n_in,
                              void* d_out, int out_size, void* d_ws, size_t ws_size,
                              hipStream_t stream) {
  const float* x      = (const float*)d_in[0];
  const int*   labels = (const int*)d_in[1];
  float* out = (float*)d_out;

  char* ws = (char*)d_ws;
  unsigned short* xb = (unsigned short*)(ws + OFF_XB);
  unsigned* gS   = (unsigned*)(ws + OFF_GS);
  unsigned* gSp  = (unsigned*)(ws + OFF_GSP);
  unsigned* gA   = (unsigned*)(ws + OFF_GA);
  unsigned* gAp  = (unsigned*)(ws + OFF_GAP);
  int*      cc   = (int*)(ws + OFF_CC);
  float*    accum = (float*)(ws + OFF_AC);
  unsigned* done  = (unsigned*)(ws + OFF_AC + 8);

  prep_kernel<<<512, 256, 0, stream>>>(x, xb, (uint4*)(ws + OFF_GS));
  fastap_main_kernel<<<dim3(NS / 64, NS / ROWCHUNK), 256, 0, stream>>>(
      xb, labels, gS, gSp, gA, gAp, cc);
  epilogue_kernel<<<NS / 256, 256, 0, stream>>>(gS, gSp, gA, gAp, labels, cc,
                                                accum, done, out);
}